// Round 11
// baseline (179.845 us; speedup 1.0000x reference)
//
#include <hip/hip_runtime.h>
#include <hip/hip_fp16.h>

#define NUM_CAMS 6
#define C_FEAT   64
#define HF       16
#define WF       44
#define NPTS     (128*128*8)   // 131072
#define FEAT_ELEMS (NUM_CAMS*C_FEAT*HF*WF)  // 270336
#define PPB      64            // points per block
#define NTHREADS 512
#define NSLICE   (NUM_CAMS * HF)   // 96 transpose slices, one (n,y) row each

// packed per (point,cam) sampling params: 16 B -> one ds_read_b128
struct alignas(16) PCP {
    __half2  wA;     // {w00, w10}
    __half2  wB;     // {w01, w11}
    int      base;   // half-elem offset of (cam,y0,x0) pixel; 0 if invalid
    unsigned flags;  // dx | (dy<<16) | (valid<<31); dx=dy=0 if invalid/OOB
};

// ---- single kernel: inline transpose (work-claimed) + project + fuse ----
// 512 threads = 64 points x 8 channel-octs; oct = tid&7 (16B), pl = tid>>3
__global__ __launch_bounds__(NTHREADS) void uvt_all(
    const float* __restrict__ in,       // img_feats (6,64,16,44)
    const float* __restrict__ ego2cam,  // (6,4,4)
    const float* __restrict__ cam2img,  // (6,4,4)
    const float* __restrict__ vox,      // (3, NPTS)
    __half* __restrict__ featsT,        // ws: (6,16,44,64) fp16
    int* __restrict__ counters,         // ws: [0]=claim, [1]=done
    float* __restrict__ out)            // (64, NPTS)
{
    // LDS union: s_pc (6 KB) lives inside s_out's 16.6 KB footprint
    __shared__ __align__(16) char ldsbuf[PPB * (C_FEAT + 1) * sizeof(float)];
    PCP   (*s_pc)[PPB]         = (PCP (*)[PPB])ldsbuf;
    float (*s_out)[C_FEAT + 1] = (float (*)[C_FEAT + 1])ldsbuf;
    __shared__ int s_slice;

    const int tid = threadIdx.x;
    const int p0  = blockIdx.x * PPB;

    // ---- stage A: first-resident blocks claim one transpose slice each ----
    if (tid == 0)
        s_slice = __hip_atomic_fetch_add(&counters[0], 1, __ATOMIC_RELAXED,
                                         __HIP_MEMORY_SCOPE_AGENT);
    __syncthreads();
    const int slice = s_slice;
    if (slice < NSLICE) {
        const int n = slice / HF, y = slice % HF;
        const float* src = in + n * C_FEAT * HF * WF + y * WF;
        __half* dst = featsT + slice * WF * C_FEAT;
        for (int e = tid; e < WF * C_FEAT; e += NTHREADS) {
            const int c = e & 63, x = e >> 6;        // write-contiguous
            dst[e] = __float2half(src[c * (HF * WF) + x]);
        }
        __syncthreads();   // barrier drains vmcnt -> all block stores at L2
        if (tid == 0)
            __hip_atomic_fetch_add(&counters[1], 1, __ATOMIC_RELEASE,
                                   __HIP_MEMORY_SCOPE_AGENT);  // wb L2 -> MALL
    }

    // ---- phase 1: per (point,cam) params; one cam per wave; inline proj ----
    if (tid < NUM_CAMS * PPB) {         // 384 threads, 6 waves
        const int cam = __builtin_amdgcn_readfirstlane(tid >> 6);
        const int lp  = tid & 63;
        const int p   = p0 + lp;

        const float* A = cam2img + cam * 16;
        const float* B = ego2cam + cam * 16;
        float M[12];
        #pragma unroll
        for (int i = 0; i < 3; ++i)
            #pragma unroll
            for (int j = 0; j < 4; ++j) {
                float s = 0.f;
                #pragma unroll
                for (int k = 0; k < 4; ++k) s += A[i*4 + k] * B[k*4 + j];
                M[i*4 + j] = s;
            }

        const float px = vox[p];
        const float py = vox[NPTS + p];
        const float pz = vox[2 * NPTS + p];
        const float ud = M[0]*px + M[1]*py + M[2]*pz  + M[3];
        const float vd = M[4]*px + M[5]*py + M[6]*pz  + M[7];
        const float d  = M[8]*px + M[9]*py + M[10]*pz + M[11];
        const float id = 1.0f / (d + 1e-6f);
        const float u  = ud * id;
        const float v  = vd * id;
        const bool valid = (d > 0.1f) && (u >= 0.f) && (u <= 703.f)
                                      && (v >= 0.f) && (v <= 255.f);
        PCP pc;
        if (valid) {
            const float x  = u * 0.0625f;
            const float y  = v * 0.0625f;
            const float xf = floorf(x), yf = floorf(y);
            const int   x0 = (int)xf,   y0 = (int)yf;
            const float wx1 = x - xf,  wy1 = y - yf;
            const float wx0 = 1.f - wx1, wy0 = 1.f - wy1;
            const bool bx = (x0 < WF - 1);
            const bool by = (y0 < HF - 1);
            pc.wA = __halves2half2(__float2half(wx0 * wy0),
                                   __float2half(bx ? wx1 * wy0 : 0.f));
            pc.wB = __halves2half2(__float2half(by ? wx0 * wy1 : 0.f),
                                   __float2half((bx && by) ? wx1 * wy1 : 0.f));
            pc.base  = ((cam * HF + y0) * WF + x0) << 6;
            pc.flags = (bx ? 64u : 0u)
                     | ((by ? (unsigned)(WF * C_FEAT) : 0u) << 16)
                     | 0x80000000u;
        } else {
            pc.wA = pc.wB = __halves2half2(__float2half(0.f), __float2half(0.f));
            pc.base = 0; pc.flags = 0u;
        }
        s_pc[cam][lp] = pc;          // one ds_write_b128
    }
    __syncthreads();

    // ---- stage B: wait until all transpose slices are published ----
    if (tid == 0) {
        while (__hip_atomic_load(&counters[1], __ATOMIC_RELAXED,
                                 __HIP_MEMORY_SCOPE_AGENT) < NSLICE)
            __builtin_amdgcn_s_sleep(8);
    }
    __syncthreads();
    __builtin_amdgcn_fence(__ATOMIC_ACQUIRE, "agent");  // no stale L2 reads

    // ---- phase 2: vmask + gated packed-half gather (round-8 proven) ----
    const int oct = tid & 7;
    const int pl  = tid >> 3;
    float2 a0 = {0.f,0.f}, a1 = {0.f,0.f}, a2 = {0.f,0.f}, a3 = {0.f,0.f};
    int cnt = 0;

    #pragma unroll
    for (int cam = 0; cam < NUM_CAMS; ++cam) {
        const PCP pc = s_pc[cam][pl];          // one ds_read_b128
        const unsigned fl = pc.flags;
        cnt += (int)(fl >> 31);
        if (fl >> 31) {                        // exec-masked
            const int dx = (int)(fl & 0xFFFFu);
            const int dy = (int)((fl >> 16) & 0x7FFFu);
            const __half* b = featsT + pc.base + (oct << 3);
            const uint4 r00 = *(const uint4*)(b);
            const uint4 r10 = *(const uint4*)(b + dx);
            const uint4 r01 = *(const uint4*)(b + dy);
            const uint4 r11 = *(const uint4*)(b + dx + dy);

            const __half2 w00 = __low2half2(pc.wA);
            const __half2 w10 = __high2half2(pc.wA);
            const __half2 w01 = __low2half2(pc.wB);
            const __half2 w11 = __high2half2(pc.wB);
            #define BC(u_) __builtin_bit_cast(__half2, u_)
            __half2 s0 = __hmul2(w00, BC(r00.x));
            s0 = __hfma2(w10, BC(r10.x), s0);
            s0 = __hfma2(w01, BC(r01.x), s0);
            s0 = __hfma2(w11, BC(r11.x), s0);
            __half2 s1 = __hmul2(w00, BC(r00.y));
            s1 = __hfma2(w10, BC(r10.y), s1);
            s1 = __hfma2(w01, BC(r01.y), s1);
            s1 = __hfma2(w11, BC(r11.y), s1);
            __half2 s2 = __hmul2(w00, BC(r00.z));
            s2 = __hfma2(w10, BC(r10.z), s2);
            s2 = __hfma2(w01, BC(r01.z), s2);
            s2 = __hfma2(w11, BC(r11.z), s2);
            __half2 s3 = __hmul2(w00, BC(r00.w));
            s3 = __hfma2(w10, BC(r10.w), s3);
            s3 = __hfma2(w01, BC(r01.w), s3);
            s3 = __hfma2(w11, BC(r11.w), s3);
            #undef BC

            const float2 f0 = __half22float2(s0);
            const float2 f1 = __half22float2(s1);
            const float2 f2 = __half22float2(s2);
            const float2 f3 = __half22float2(s3);
            a0.x += f0.x; a0.y += f0.y;
            a1.x += f1.x; a1.y += f1.y;
            a2.x += f2.x; a2.y += f2.y;
            a3.x += f3.x; a3.y += f3.y;
        }
    }
    __syncthreads();   // all s_pc reads done before s_out overwrites union

    // ---- phase 3: transpose through LDS, 256 B-coalesced stores ----
    const float inv = 1.0f / (float)(cnt > 0 ? cnt : 1);
    const int cb = oct << 3;
    s_out[pl][cb + 0] = a0.x * inv;
    s_out[pl][cb + 1] = a0.y * inv;
    s_out[pl][cb + 2] = a1.x * inv;
    s_out[pl][cb + 3] = a1.y * inv;
    s_out[pl][cb + 4] = a2.x * inv;
    s_out[pl][cb + 5] = a2.y * inv;
    s_out[pl][cb + 6] = a3.x * inv;
    s_out[pl][cb + 7] = a3.y * inv;
    __syncthreads();

    #pragma unroll
    for (int i = 0; i < 8; ++i) {
        const int idx = tid + NTHREADS * i;   // 0..4095
        const int c   = idx >> 6;             // channel
        const int lp  = idx & 63;             // point (64 consecutive per wave)
        out[c * NPTS + p0 + lp] = s_out[lp][c];
    }
}

// ---------------------------------------------------------------------------
extern "C" void kernel_launch(void* const* d_in, const int* in_sizes, int n_in,
                              void* d_out, int out_size, void* d_ws, size_t ws_size,
                              hipStream_t stream) {
    const float* img_feats = (const float*)d_in[0];  // (6,64,16,44)
    const float* ego2cam   = (const float*)d_in[1];  // (6,4,4)
    const float* cam2img   = (const float*)d_in[2];  // (6,4,4)
    const float* vox       = (const float*)d_in[3];  // (3,8,128,128)
    float* out = (float*)d_out;                      // (1,64,8,128,128)

    __half* featsT   = (__half*)d_ws;                // 540672 B
    int*    counters = (int*)((char*)d_ws + 544768); // 8 B, cacheline-separated

    hipMemsetAsync(counters, 0, 8, stream);          // graph-capturable
    uvt_all<<<NPTS / PPB, NTHREADS, 0, stream>>>(img_feats, ego2cam, cam2img,
                                                 vox, featsT, counters, out);
}

// Round 12
// 20.780 us; speedup vs baseline: 8.6546x; 8.6546x over previous
//
#include <hip/hip_runtime.h>
#include <hip/hip_fp16.h>

#define NUM_CAMS 6
#define C_FEAT   64
#define HF       16
#define WF       44
#define NPTS     (128*128*8)   // 131072
#define FEAT_ELEMS (NUM_CAMS*C_FEAT*HF*WF)  // 270336
#define PPB      64            // points per block
#define NTHREADS 512

// ---- kernel 1: LDS-tiled transpose (N,C,H,W)->(N,H,W,C) fp16 + proj matmul ----
// blocks 0..95: one (n,y) slice each (coalesced reads AND writes); block 96: proj.
__global__ __launch_bounds__(256) void uvt_prep(const float* __restrict__ in,
                                                const float* __restrict__ ego2cam,
                                                const float* __restrict__ cam2img,
                                                __half* __restrict__ featsT,
                                                float* __restrict__ projws) {
    const int blk = blockIdx.x;
    if (blk < NUM_CAMS * HF) {
        __shared__ float s[WF][C_FEAT + 1];
        const int n = blk / HF, y = blk % HF;
        const float* src = in + n * C_FEAT * HF * WF + y * WF;
        for (int e = threadIdx.x; e < C_FEAT * WF; e += 256) {
            const int c = e / WF, x = e - c * WF;     // x-contiguous reads
            s[x][c] = src[c * (HF * WF) + x];
        }
        __syncthreads();
        __half* dst = featsT + (n * HF + y) * WF * C_FEAT;
        for (int e = threadIdx.x; e < C_FEAT * WF; e += 256) {
            const int x = e >> 6, c = e & 63;         // contiguous fp16 writes
            dst[e] = __float2half(s[x][c]);
        }
    } else {
        const int t = threadIdx.x;
        if (t < NUM_CAMS * 12) {
            const int cam = t / 12, e = t - cam * 12;
            const int i = e >> 2, j = e & 3;
            const float* A = cam2img + cam * 16;
            const float* B = ego2cam + cam * 16;
            float sum = 0.f;
            #pragma unroll
            for (int k = 0; k < 4; ++k) sum += A[i*4 + k] * B[k*4 + j];
            projws[cam * 12 + e] = sum;
        }
    }
}

// packed per (point,cam) sampling params: 16 B -> one ds_read_b128
struct alignas(16) PCP {
    __half2  wA;     // {w00, w10}
    __half2  wB;     // {w01, w11}
    int      base;   // half-elem offset of (cam,y0,x0) pixel; 0 if invalid
    unsigned flags;  // dx | (dy<<16) | (valid<<31); dx=dy=0 if invalid/OOB
};

// ---- kernel 2: project + gated packed-half bilinear + fuse ----
// 512 threads = 64 points x 8 channel-octs; oct = tid&7 (16B), pl = tid>>3
__global__ __launch_bounds__(NTHREADS) void uvt_fuse(
    const __half* __restrict__ featsT,  // (6,16,44,64) fp16
    const float* __restrict__ projws,   // (6,3,4)
    const float* __restrict__ vox,      // (3, NPTS)
    float* __restrict__ out)            // (64, NPTS)
{
    // LDS union: s_pc (6 KB) lives inside s_out's 16.6 KB footprint
    __shared__ __align__(16) char ldsbuf[PPB * (C_FEAT + 1) * sizeof(float)];
    PCP   (*s_pc)[PPB]         = (PCP (*)[PPB])ldsbuf;
    float (*s_out)[C_FEAT + 1] = (float (*)[C_FEAT + 1])ldsbuf;

    const int tid = threadIdx.x;
    const int p0  = blockIdx.x * PPB;

    // ---- phase 1: per (point,cam) params; one cam per wave -> scalar proj ----
    if (tid < NUM_CAMS * PPB) {         // 384 threads, 6 waves
        const int cam = __builtin_amdgcn_readfirstlane(tid >> 6);
        const int lp  = tid & 63;
        const int p   = p0 + lp;
        const float* M = projws + cam * 12;

        const float px = vox[p];
        const float py = vox[NPTS + p];
        const float pz = vox[2 * NPTS + p];
        const float ud = M[0]*px + M[1]*py + M[2]*pz  + M[3];
        const float vd = M[4]*px + M[5]*py + M[6]*pz  + M[7];
        const float d  = M[8]*px + M[9]*py + M[10]*pz + M[11];
        const float id = 1.0f / (d + 1e-6f);
        const float u  = ud * id;
        const float v  = vd * id;
        const bool valid = (d > 0.1f) && (u >= 0.f) && (u <= 703.f)
                                      && (v >= 0.f) && (v <= 255.f);
        PCP pc;
        if (valid) {
            const float x  = u * 0.0625f;
            const float y  = v * 0.0625f;
            const float xf = floorf(x), yf = floorf(y);
            const int   x0 = (int)xf,   y0 = (int)yf;
            const float wx1 = x - xf,  wy1 = y - yf;
            const float wx0 = 1.f - wx1, wy0 = 1.f - wy1;
            const bool bx = (x0 < WF - 1);
            const bool by = (y0 < HF - 1);
            pc.wA = __halves2half2(__float2half(wx0 * wy0),
                                   __float2half(bx ? wx1 * wy0 : 0.f));
            pc.wB = __halves2half2(__float2half(by ? wx0 * wy1 : 0.f),
                                   __float2half((bx && by) ? wx1 * wy1 : 0.f));
            pc.base  = ((cam * HF + y0) * WF + x0) << 6;
            pc.flags = (bx ? 64u : 0u)
                     | ((by ? (unsigned)(WF * C_FEAT) : 0u) << 16)
                     | 0x80000000u;
        } else {
            pc.wA = pc.wB = __halves2half2(__float2half(0.f), __float2half(0.f));
            pc.base = 0; pc.flags = 0u;
        }
        s_pc[cam][lp] = pc;          // one ds_write_b128
    }
    __syncthreads();

    // ---- phase 2: vmask + gated packed-half gather (round-8 proven) ----
    const int oct = tid & 7;
    const int pl  = tid >> 3;
    float2 a0 = {0.f,0.f}, a1 = {0.f,0.f}, a2 = {0.f,0.f}, a3 = {0.f,0.f};
    int cnt = 0;

    #pragma unroll
    for (int cam = 0; cam < NUM_CAMS; ++cam) {
        const PCP pc = s_pc[cam][pl];          // one ds_read_b128
        const unsigned fl = pc.flags;
        cnt += (int)(fl >> 31);
        if (fl >> 31) {                        // exec-masked
            const int dx = (int)(fl & 0xFFFFu);
            const int dy = (int)((fl >> 16) & 0x7FFFu);
            const __half* b = featsT + pc.base + (oct << 3);
            const uint4 r00 = *(const uint4*)(b);
            const uint4 r10 = *(const uint4*)(b + dx);
            const uint4 r01 = *(const uint4*)(b + dy);
            const uint4 r11 = *(const uint4*)(b + dx + dy);

            const __half2 w00 = __low2half2(pc.wA);
            const __half2 w10 = __high2half2(pc.wA);
            const __half2 w01 = __low2half2(pc.wB);
            const __half2 w11 = __high2half2(pc.wB);
            #define BC(u_) __builtin_bit_cast(__half2, u_)
            __half2 s0 = __hmul2(w00, BC(r00.x));
            s0 = __hfma2(w10, BC(r10.x), s0);
            s0 = __hfma2(w01, BC(r01.x), s0);
            s0 = __hfma2(w11, BC(r11.x), s0);
            __half2 s1 = __hmul2(w00, BC(r00.y));
            s1 = __hfma2(w10, BC(r10.y), s1);
            s1 = __hfma2(w01, BC(r01.y), s1);
            s1 = __hfma2(w11, BC(r11.y), s1);
            __half2 s2 = __hmul2(w00, BC(r00.z));
            s2 = __hfma2(w10, BC(r10.z), s2);
            s2 = __hfma2(w01, BC(r01.z), s2);
            s2 = __hfma2(w11, BC(r11.z), s2);
            __half2 s3 = __hmul2(w00, BC(r00.w));
            s3 = __hfma2(w10, BC(r10.w), s3);
            s3 = __hfma2(w01, BC(r01.w), s3);
            s3 = __hfma2(w11, BC(r11.w), s3);
            #undef BC

            const float2 f0 = __half22float2(s0);
            const float2 f1 = __half22float2(s1);
            const float2 f2 = __half22float2(s2);
            const float2 f3 = __half22float2(s3);
            a0.x += f0.x; a0.y += f0.y;
            a1.x += f1.x; a1.y += f1.y;
            a2.x += f2.x; a2.y += f2.y;
            a3.x += f3.x; a3.y += f3.y;
        }
    }
    __syncthreads();   // all s_pc reads done before s_out overwrites union

    // ---- phase 3: transpose through LDS, float4 coalesced stores ----
    const float inv = 1.0f / (float)(cnt > 0 ? cnt : 1);
    const int cb = oct << 3;
    s_out[pl][cb + 0] = a0.x * inv;
    s_out[pl][cb + 1] = a0.y * inv;
    s_out[pl][cb + 2] = a1.x * inv;
    s_out[pl][cb + 3] = a1.y * inv;
    s_out[pl][cb + 4] = a2.x * inv;
    s_out[pl][cb + 5] = a2.y * inv;
    s_out[pl][cb + 6] = a3.x * inv;
    s_out[pl][cb + 7] = a3.y * inv;
    __syncthreads();

    // 1024 float4 chunks = 64 channels x 16 point-groups; 2 per thread.
    // LDS reads stride-65: bank = (4g + c + i) mod 32, 4g+c distinct -> 2-way, free.
    #pragma unroll
    for (int i = 0; i < 2; ++i) {
        const int idx = tid + NTHREADS * i;   // 0..1023
        const int c   = idx >> 4;             // channel
        const int g   = idx & 15;             // point-group (4 consecutive points)
        float4 vq;
        vq.x = s_out[4*g + 0][c];
        vq.y = s_out[4*g + 1][c];
        vq.z = s_out[4*g + 2][c];
        vq.w = s_out[4*g + 3][c];
        *(float4*)(&out[c * NPTS + p0 + 4*g]) = vq;   // 256B segments/wave
    }
}

// ---------------------------------------------------------------------------
extern "C" void kernel_launch(void* const* d_in, const int* in_sizes, int n_in,
                              void* d_out, int out_size, void* d_ws, size_t ws_size,
                              hipStream_t stream) {
    const float* img_feats = (const float*)d_in[0];  // (6,64,16,44)
    const float* ego2cam   = (const float*)d_in[1];  // (6,4,4)
    const float* cam2img   = (const float*)d_in[2];  // (6,4,4)
    const float* vox       = (const float*)d_in[3];  // (3,8,128,128)
    float* out = (float*)d_out;                      // (1,64,8,128,128)

    __half* featsT = (__half*)d_ws;                  // 270336 halves
    float*  projws = (float*)((char*)d_ws + FEAT_ELEMS * sizeof(__half)); // 72 floats

    uvt_prep<<<NUM_CAMS * HF + 1, 256, 0, stream>>>(img_feats, ego2cam, cam2img,
                                                    featsT, projws);
    uvt_fuse<<<NPTS / PPB, NTHREADS, 0, stream>>>(featsT, projws, vox, out);
}

// Round 13
// 19.707 us; speedup vs baseline: 9.1262x; 1.0545x over previous
//
#include <hip/hip_runtime.h>
#include <hip/hip_fp16.h>

#define NUM_CAMS 6
#define C_FEAT   64
#define HF       16
#define WF       44
#define NPTS     (128*128*8)   // 131072
#define FEAT_ELEMS (NUM_CAMS*C_FEAT*HF*WF)  // 270336
#define PPB      64            // points per block
#define NTHREADS 512

// ---- kernel 1: flat transpose+fp16 convert (full grid) + proj matmul ----
// (round-8 proven: 1057 blocks saturate all CUs; scattered reads are L2-absorbed)
__global__ __launch_bounds__(256) void uvt_prep(const float* __restrict__ in,
                                                const float* __restrict__ ego2cam,
                                                const float* __restrict__ cam2img,
                                                __half* __restrict__ featsT,
                                                float* __restrict__ projws) {
    const int blk = blockIdx.x;
    if (blk < FEAT_ELEMS / 256) {
        const int g   = blk * 256 + threadIdx.x;
        const int c   = g & 63;
        const int pix = g >> 6;
        const int x   = pix % WF;
        const int t2  = pix / WF;
        const int y   = t2 % HF;
        const int n   = t2 / HF;
        featsT[g] = __float2half(in[((n * C_FEAT + c) * HF + y) * WF + x]);
    } else {
        const int t = threadIdx.x;
        if (t < NUM_CAMS * 12) {
            const int cam = t / 12, e = t - cam * 12;
            const int i = e >> 2, j = e & 3;
            const float* A = cam2img + cam * 16;
            const float* B = ego2cam + cam * 16;
            float sum = 0.f;
            #pragma unroll
            for (int k = 0; k < 4; ++k) sum += A[i*4 + k] * B[k*4 + j];
            projws[cam * 12 + e] = sum;
        }
    }
}

// packed per (point,cam) sampling params: 16 B -> one ds_read_b128
struct alignas(16) PCP {
    __half2  wA;     // {w00, w10}
    __half2  wB;     // {w01, w11}
    int      base;   // half-elem offset of (cam,y0,x0) pixel; 0 if invalid
    unsigned flags;  // dx | (dy<<16) | (valid<<31); dx=dy=0 if invalid/OOB
};

// ---- kernel 2: project + gated packed-half bilinear + fuse ----
// 512 threads = 64 points x 8 channel-octs; oct = tid&7 (16B), pl = tid>>3
__global__ __launch_bounds__(NTHREADS) void uvt_fuse(
    const __half* __restrict__ featsT,  // (6,16,44,64) fp16
    const float* __restrict__ projws,   // (6,3,4)
    const float* __restrict__ vox,      // (3, NPTS)
    float* __restrict__ out)            // (64, NPTS)
{
    // LDS union: s_pc (6 KB) lives inside s_out's 16.6 KB footprint
    __shared__ __align__(16) char ldsbuf[PPB * (C_FEAT + 1) * sizeof(float)];
    PCP   (*s_pc)[PPB]         = (PCP (*)[PPB])ldsbuf;
    float (*s_out)[C_FEAT + 1] = (float (*)[C_FEAT + 1])ldsbuf;

    const int tid = threadIdx.x;
    const int p0  = blockIdx.x * PPB;

    // ---- phase 1: per (point,cam) params; one cam per wave -> scalar proj ----
    if (tid < NUM_CAMS * PPB) {         // 384 threads, 6 waves
        const int cam = __builtin_amdgcn_readfirstlane(tid >> 6);
        const int lp  = tid & 63;
        const int p   = p0 + lp;
        const float* M = projws + cam * 12;

        const float px = vox[p];
        const float py = vox[NPTS + p];
        const float pz = vox[2 * NPTS + p];
        const float ud = M[0]*px + M[1]*py + M[2]*pz  + M[3];
        const float vd = M[4]*px + M[5]*py + M[6]*pz  + M[7];
        const float d  = M[8]*px + M[9]*py + M[10]*pz + M[11];
        const float id = 1.0f / (d + 1e-6f);
        const float u  = ud * id;
        const float v  = vd * id;
        const bool valid = (d > 0.1f) && (u >= 0.f) && (u <= 703.f)
                                      && (v >= 0.f) && (v <= 255.f);
        PCP pc;
        if (valid) {
            const float x  = u * 0.0625f;
            const float y  = v * 0.0625f;
            const float xf = floorf(x), yf = floorf(y);
            const int   x0 = (int)xf,   y0 = (int)yf;
            const float wx1 = x - xf,  wy1 = y - yf;
            const float wx0 = 1.f - wx1, wy0 = 1.f - wy1;
            const bool bx = (x0 < WF - 1);
            const bool by = (y0 < HF - 1);
            pc.wA = __halves2half2(__float2half(wx0 * wy0),
                                   __float2half(bx ? wx1 * wy0 : 0.f));
            pc.wB = __halves2half2(__float2half(by ? wx0 * wy1 : 0.f),
                                   __float2half((bx && by) ? wx1 * wy1 : 0.f));
            pc.base  = ((cam * HF + y0) * WF + x0) << 6;
            pc.flags = (bx ? 64u : 0u)
                     | ((by ? (unsigned)(WF * C_FEAT) : 0u) << 16)
                     | 0x80000000u;
        } else {
            pc.wA = pc.wB = __halves2half2(__float2half(0.f), __float2half(0.f));
            pc.base = 0; pc.flags = 0u;
        }
        s_pc[cam][lp] = pc;          // one ds_write_b128
    }
    __syncthreads();

    // ---- phase 2: vmask + gated packed-half gather (round-8 proven) ----
    const int oct = tid & 7;
    const int pl  = tid >> 3;
    float2 a0 = {0.f,0.f}, a1 = {0.f,0.f}, a2 = {0.f,0.f}, a3 = {0.f,0.f};
    int cnt = 0;

    #pragma unroll
    for (int cam = 0; cam < NUM_CAMS; ++cam) {
        const PCP pc = s_pc[cam][pl];          // one ds_read_b128
        const unsigned fl = pc.flags;
        cnt += (int)(fl >> 31);
        if (fl >> 31) {                        // exec-masked
            const int dx = (int)(fl & 0xFFFFu);
            const int dy = (int)((fl >> 16) & 0x7FFFu);
            const __half* b = featsT + pc.base + (oct << 3);
            const uint4 r00 = *(const uint4*)(b);
            const uint4 r10 = *(const uint4*)(b + dx);
            const uint4 r01 = *(const uint4*)(b + dy);
            const uint4 r11 = *(const uint4*)(b + dx + dy);

            const __half2 w00 = __low2half2(pc.wA);
            const __half2 w10 = __high2half2(pc.wA);
            const __half2 w01 = __low2half2(pc.wB);
            const __half2 w11 = __high2half2(pc.wB);
            #define BC(u_) __builtin_bit_cast(__half2, u_)
            __half2 s0 = __hmul2(w00, BC(r00.x));
            s0 = __hfma2(w10, BC(r10.x), s0);
            s0 = __hfma2(w01, BC(r01.x), s0);
            s0 = __hfma2(w11, BC(r11.x), s0);
            __half2 s1 = __hmul2(w00, BC(r00.y));
            s1 = __hfma2(w10, BC(r10.y), s1);
            s1 = __hfma2(w01, BC(r01.y), s1);
            s1 = __hfma2(w11, BC(r11.y), s1);
            __half2 s2 = __hmul2(w00, BC(r00.z));
            s2 = __hfma2(w10, BC(r10.z), s2);
            s2 = __hfma2(w01, BC(r01.z), s2);
            s2 = __hfma2(w11, BC(r11.z), s2);
            __half2 s3 = __hmul2(w00, BC(r00.w));
            s3 = __hfma2(w10, BC(r10.w), s3);
            s3 = __hfma2(w01, BC(r01.w), s3);
            s3 = __hfma2(w11, BC(r11.w), s3);
            #undef BC

            const float2 f0 = __half22float2(s0);
            const float2 f1 = __half22float2(s1);
            const float2 f2 = __half22float2(s2);
            const float2 f3 = __half22float2(s3);
            a0.x += f0.x; a0.y += f0.y;
            a1.x += f1.x; a1.y += f1.y;
            a2.x += f2.x; a2.y += f2.y;
            a3.x += f3.x; a3.y += f3.y;
        }
    }
    __syncthreads();   // all s_pc reads done before s_out overwrites union

    // ---- phase 3: transpose through LDS, float4 coalesced stores ----
    const float inv = 1.0f / (float)(cnt > 0 ? cnt : 1);
    const int cb = oct << 3;
    s_out[pl][cb + 0] = a0.x * inv;
    s_out[pl][cb + 1] = a0.y * inv;
    s_out[pl][cb + 2] = a1.x * inv;
    s_out[pl][cb + 3] = a1.y * inv;
    s_out[pl][cb + 4] = a2.x * inv;
    s_out[pl][cb + 5] = a2.y * inv;
    s_out[pl][cb + 6] = a3.x * inv;
    s_out[pl][cb + 7] = a3.y * inv;
    __syncthreads();

    // 1024 float4 chunks = 64 channels x 16 point-groups; 2 per thread.
    // LDS reads stride-65: bank = (4g+j+c) mod 32, 4g+(l>>4) spans 0..63 -> 2-way, free.
    #pragma unroll
    for (int i = 0; i < 2; ++i) {
        const int idx = tid + NTHREADS * i;   // 0..1023
        const int c   = idx >> 4;             // channel
        const int g   = idx & 15;             // point-group (4 consecutive points)
        float4 vq;
        vq.x = s_out[4*g + 0][c];
        vq.y = s_out[4*g + 1][c];
        vq.z = s_out[4*g + 2][c];
        vq.w = s_out[4*g + 3][c];
        *(float4*)(&out[c * NPTS + p0 + 4*g]) = vq;   // 4 x 256B segments/wave
    }
}

// ---------------------------------------------------------------------------
extern "C" void kernel_launch(void* const* d_in, const int* in_sizes, int n_in,
                              void* d_out, int out_size, void* d_ws, size_t ws_size,
                              hipStream_t stream) {
    const float* img_feats = (const float*)d_in[0];  // (6,64,16,44)
    const float* ego2cam   = (const float*)d_in[1];  // (6,4,4)
    const float* cam2img   = (const float*)d_in[2];  // (6,4,4)
    const float* vox       = (const float*)d_in[3];  // (3,8,128,128)
    float* out = (float*)d_out;                      // (1,64,8,128,128)

    __half* featsT = (__half*)d_ws;                  // 270336 halves
    float*  projws = (float*)((char*)d_ws + FEAT_ELEMS * sizeof(__half)); // 72 floats

    uvt_prep<<<FEAT_ELEMS / 256 + 1, 256, 0, stream>>>(img_feats, ego2cam, cam2img,
                                                       featsT, projws);
    uvt_fuse<<<NPTS / PPB, NTHREADS, 0, stream>>>(featsT, projws, vox, out);
}

// Round 14
// 19.541 us; speedup vs baseline: 9.2035x; 1.0085x over previous
//
#include <hip/hip_runtime.h>
#include <hip/hip_fp16.h>

#define NUM_CAMS 6
#define C_FEAT   64
#define HF       16
#define WF       44
#define NPTS     (128*128*8)   // 131072
#define FEAT_ELEMS (NUM_CAMS*C_FEAT*HF*WF)  // 270336
#define PPB      32            // points per block
#define NTHREADS 256

// ---- kernel 1: flat transpose+fp16 convert (full grid) + proj matmul ----
// (round-8 proven: 1057 blocks saturate all CUs; scattered reads are L2-absorbed)
__global__ __launch_bounds__(256) void uvt_prep(const float* __restrict__ in,
                                                const float* __restrict__ ego2cam,
                                                const float* __restrict__ cam2img,
                                                __half* __restrict__ featsT,
                                                float* __restrict__ projws) {
    const int blk = blockIdx.x;
    if (blk < FEAT_ELEMS / 256) {
        const int g   = blk * 256 + threadIdx.x;
        const int c   = g & 63;
        const int pix = g >> 6;
        const int x   = pix % WF;
        const int t2  = pix / WF;
        const int y   = t2 % HF;
        const int n   = t2 / HF;
        featsT[g] = __float2half(in[((n * C_FEAT + c) * HF + y) * WF + x]);
    } else {
        const int t = threadIdx.x;
        if (t < NUM_CAMS * 12) {
            const int cam = t / 12, e = t - cam * 12;
            const int i = e >> 2, j = e & 3;
            const float* A = cam2img + cam * 16;
            const float* B = ego2cam + cam * 16;
            float sum = 0.f;
            #pragma unroll
            for (int k = 0; k < 4; ++k) sum += A[i*4 + k] * B[k*4 + j];
            projws[cam * 12 + e] = sum;
        }
    }
}

// packed per (point,cam) sampling params: 16 B -> one ds_read_b128
struct alignas(16) PCP {
    __half2  wA;     // {w00, w10}
    __half2  wB;     // {w01, w11}
    int      base;   // half-elem offset of (cam,y0,x0) pixel; 0 if invalid
    unsigned flags;  // dx | (dy<<16) | (valid<<31); dx=dy=0 if invalid/OOB
};

// ---- kernel 2: project + bit-scan gated bilinear + fuse ----
// 256 threads = 32 points x 8 channel-octs; oct = tid&7 (16B), pl = tid>>3
// 8 resident blocks/CU -> fine-grained cross-block phase overlap
__global__ __launch_bounds__(NTHREADS) void uvt_fuse(
    const __half* __restrict__ featsT,  // (6,16,44,64) fp16
    const float* __restrict__ projws,   // (6,3,4)
    const float* __restrict__ vox,      // (3, NPTS)
    float* __restrict__ out)            // (64, NPTS)
{
    __shared__ __align__(16) PCP  s_pc[NUM_CAMS][PPB];   // 3 KB
    __shared__ float s_out[PPB][C_FEAT + 1];             // 8.3 KB (no union -> one less barrier)

    const int tid = threadIdx.x;
    const int p0  = blockIdx.x * PPB;

    // ---- phase 1: per (point,cam) params; 192 threads (cam = tid>>5) ----
    if (tid < NUM_CAMS * PPB) {
        const int cam = tid >> 5;
        const int lp  = tid & 31;
        const int p   = p0 + lp;
        const float* M = projws + cam * 12;

        const float px = vox[p];
        const float py = vox[NPTS + p];
        const float pz = vox[2 * NPTS + p];
        const float ud = M[0]*px + M[1]*py + M[2]*pz  + M[3];
        const float vd = M[4]*px + M[5]*py + M[6]*pz  + M[7];
        const float d  = M[8]*px + M[9]*py + M[10]*pz + M[11];
        const float id = 1.0f / (d + 1e-6f);
        const float u  = ud * id;
        const float v  = vd * id;
        const bool valid = (d > 0.1f) && (u >= 0.f) && (u <= 703.f)
                                      && (v >= 0.f) && (v <= 255.f);
        PCP pc;
        if (valid) {
            const float x  = u * 0.0625f;
            const float y  = v * 0.0625f;
            const float xf = floorf(x), yf = floorf(y);
            const int   x0 = (int)xf,   y0 = (int)yf;
            const float wx1 = x - xf,  wy1 = y - yf;
            const float wx0 = 1.f - wx1, wy0 = 1.f - wy1;
            const bool bx = (x0 < WF - 1);
            const bool by = (y0 < HF - 1);
            pc.wA = __halves2half2(__float2half(wx0 * wy0),
                                   __float2half(bx ? wx1 * wy0 : 0.f));
            pc.wB = __halves2half2(__float2half(by ? wx0 * wy1 : 0.f),
                                   __float2half((bx && by) ? wx1 * wy1 : 0.f));
            pc.base  = ((cam * HF + y0) * WF + x0) << 6;
            pc.flags = (bx ? 64u : 0u)
                     | ((by ? (unsigned)(WF * C_FEAT) : 0u) << 16)
                     | 0x80000000u;
        } else {
            pc.wA = pc.wB = __halves2half2(__float2half(0.f), __float2half(0.f));
            pc.base = 0; pc.flags = 0u;
        }
        s_pc[cam][lp] = pc;          // one ds_write_b128
    }
    __syncthreads();

    // ---- phase 2: build valid-bit mask (cheap b32 reads), bit-scan gather ----
    const int oct = tid & 7;
    const int pl  = tid >> 3;
    unsigned vm = 0;
    #pragma unroll
    for (int cam = 0; cam < NUM_CAMS; ++cam)
        vm |= (s_pc[cam][pl].flags >> 31) << cam;   // ds_read_b32 each
    const int cnt = __popc(vm);
    const float inv = 1.0f / (float)(cnt > 0 ? cnt : 1);

    float2 a0 = {0.f,0.f}, a1 = {0.f,0.f}, a2 = {0.f,0.f}, a3 = {0.f,0.f};

    // ascending-cam bit loop: accumulation order identical to cam 0..5 loop
    for (unsigned m = vm; m; m &= m - 1) {
        const int cam = (int)__builtin_ctz(m);
        const PCP pc = s_pc[cam][pl];          // one ds_read_b128 (valid entries only)
        const unsigned fl = pc.flags;
        const int dx = (int)(fl & 0xFFFFu);
        const int dy = (int)((fl >> 16) & 0x7FFFu);
        const __half* b = featsT + pc.base + (oct << 3);
        const uint4 r00 = *(const uint4*)(b);
        const uint4 r10 = *(const uint4*)(b + dx);
        const uint4 r01 = *(const uint4*)(b + dy);
        const uint4 r11 = *(const uint4*)(b + dx + dy);

        const __half2 w00 = __low2half2(pc.wA);
        const __half2 w10 = __high2half2(pc.wA);
        const __half2 w01 = __low2half2(pc.wB);
        const __half2 w11 = __high2half2(pc.wB);
        #define BC(u_) __builtin_bit_cast(__half2, u_)
        __half2 s0 = __hmul2(w00, BC(r00.x));
        s0 = __hfma2(w10, BC(r10.x), s0);
        s0 = __hfma2(w01, BC(r01.x), s0);
        s0 = __hfma2(w11, BC(r11.x), s0);
        __half2 s1 = __hmul2(w00, BC(r00.y));
        s1 = __hfma2(w10, BC(r10.y), s1);
        s1 = __hfma2(w01, BC(r01.y), s1);
        s1 = __hfma2(w11, BC(r11.y), s1);
        __half2 s2 = __hmul2(w00, BC(r00.z));
        s2 = __hfma2(w10, BC(r10.z), s2);
        s2 = __hfma2(w01, BC(r01.z), s2);
        s2 = __hfma2(w11, BC(r11.z), s2);
        __half2 s3 = __hmul2(w00, BC(r00.w));
        s3 = __hfma2(w10, BC(r10.w), s3);
        s3 = __hfma2(w01, BC(r01.w), s3);
        s3 = __hfma2(w11, BC(r11.w), s3);
        #undef BC

        const float2 f0 = __half22float2(s0);
        const float2 f1 = __half22float2(s1);
        const float2 f2 = __half22float2(s2);
        const float2 f3 = __half22float2(s3);
        a0.x += f0.x; a0.y += f0.y;
        a1.x += f1.x; a1.y += f1.y;
        a2.x += f2.x; a2.y += f2.y;
        a3.x += f3.x; a3.y += f3.y;
    }

    // ---- phase 3: transpose through LDS, float4 coalesced stores ----
    const int cb = oct << 3;
    s_out[pl][cb + 0] = a0.x * inv;
    s_out[pl][cb + 1] = a0.y * inv;
    s_out[pl][cb + 2] = a1.x * inv;
    s_out[pl][cb + 3] = a1.y * inv;
    s_out[pl][cb + 4] = a2.x * inv;
    s_out[pl][cb + 5] = a2.y * inv;
    s_out[pl][cb + 6] = a3.x * inv;
    s_out[pl][cb + 7] = a3.y * inv;
    __syncthreads();

    // 512 float4 chunks = 64 channels x 8 point-groups; 2 per thread.
    // wave: 8 channels x full 32-pt rows -> 8 x 128B segments per store instr.
    #pragma unroll
    for (int i = 0; i < 2; ++i) {
        const int idx = tid + NTHREADS * i;   // 0..511
        const int c   = idx >> 3;             // channel
        const int g   = idx & 7;              // point-group (4 consecutive points)
        float4 vq;
        vq.x = s_out[4*g + 0][c];
        vq.y = s_out[4*g + 1][c];
        vq.z = s_out[4*g + 2][c];
        vq.w = s_out[4*g + 3][c];
        *(float4*)(&out[c * NPTS + p0 + 4*g]) = vq;
    }
}

// ---------------------------------------------------------------------------
extern "C" void kernel_launch(void* const* d_in, const int* in_sizes, int n_in,
                              void* d_out, int out_size, void* d_ws, size_t ws_size,
                              hipStream_t stream) {
    const float* img_feats = (const float*)d_in[0];  // (6,64,16,44)
    const float* ego2cam   = (const float*)d_in[1];  // (6,4,4)
    const float* cam2img   = (const float*)d_in[2];  // (6,4,4)
    const float* vox       = (const float*)d_in[3];  // (3,8,128,128)
    float* out = (float*)d_out;                      // (1,64,8,128,128)

    __half* featsT = (__half*)d_ws;                  // 270336 halves
    float*  projws = (float*)((char*)d_ws + FEAT_ELEMS * sizeof(__half)); // 72 floats

    uvt_prep<<<FEAT_ELEMS / 256 + 1, 256, 0, stream>>>(img_feats, ego2cam, cam2img,
                                                       featsT, projws);
    uvt_fuse<<<NPTS / PPB, NTHREADS, 0, stream>>>(featsT, projws, vox, out);
}